// Round 11
// baseline (1319.239 us; speedup 1.0000x reference)
//
#include <hip/hip_runtime.h>
#include <hip/hip_bf16.h>
#include <cfloat>
#include <climits>

typedef short short8 __attribute__((ext_vector_type(8)));
typedef float f32x4 __attribute__((ext_vector_type(4)));

#define TKK 64
#define CAND 512        // candidate cap per row (mean ~231 at t=2.35, 18 sigma headroom)
#define BANDCAP 128     // padded sort width for boundary band (band mean ~16)
#define TCOLLECT 2.35f  // collection threshold on approx (bf16-screen) z
#define QBASE 2.34f
#define QSCALE 16384.0f
#define DELTA 0.04f     // half-width of ambiguity band (~25 sigma of approx error)

// direct global->LDS async copy, 16B per lane, LDS dst = wave-uniform base + lane*16
__device__ __forceinline__ void load_lds16(const void* g, void* l) {
    __builtin_amdgcn_global_load_lds(
        (const __attribute__((address_space(1))) unsigned int*)g,
        (__attribute__((address_space(3))) unsigned int*)l, 16, 0, 0);
}

// packed candidate key: [31:15] quantized approx value, [14:0] = 0x7FFF - idx
__device__ __forceinline__ float key_val(unsigned k) {
    return (float)(k >> 15) * (1.0f / QSCALE) + QBASE;
}
__device__ __forceinline__ int key_idx(unsigned k) {
    return 0x7FFF - (int)(k & 0x7FFFu);
}

__device__ __forceinline__ float bf2f(unsigned short u) {
    return __uint_as_float((unsigned)u << 16);
}

// ---------------------------------------------------------------------------
// prep: f32 -> bf16 elementwise (used for x and for W_dec)
// ---------------------------------------------------------------------------
__global__ __launch_bounds__(256) void cvt_bf16(const float* __restrict__ X,
                                                __hip_bfloat16* __restrict__ Xb,
                                                size_t n)
{
    size_t i = ((size_t)blockIdx.x * 256 + threadIdx.x) * 4;
    if (i + 3 < n) {
        float4 v = *(const float4*)(X + i);
        __hip_bfloat16 t[4] = { __float2bfloat16(v.x), __float2bfloat16(v.y),
                                __float2bfloat16(v.z), __float2bfloat16(v.w) };
        *(uint2*)(Xb + i) = *(uint2*)t;
    }
}

// ---------------------------------------------------------------------------
// prep: W_enc [K][F] -> WTf [F][K] (f32) and WTb [F][K] (bf16)
// ---------------------------------------------------------------------------
__global__ __launch_bounds__(256) void transpose_W(
    const float* __restrict__ W, float* __restrict__ WTf,
    __hip_bfloat16* __restrict__ WTb, int K, int F)
{
    __shared__ float t[32][33];
    const int x0 = blockIdx.x * 32;   // feature block
    const int y0 = blockIdx.y * 32;   // k block
    const int tx = threadIdx.x & 31, ty = threadIdx.x >> 5;  // 32 x 8
#pragma unroll
    for (int i = 0; i < 4; ++i)
        t[ty + i * 8][tx] = W[(size_t)(y0 + ty + i * 8) * F + x0 + tx];
    __syncthreads();
#pragma unroll
    for (int i = 0; i < 4; ++i) {
        float v = t[tx][ty + i * 8];
        size_t o = (size_t)(x0 + ty + i * 8) * K + y0 + tx;
        WTf[o] = v;
        WTb[o] = __float2bfloat16(v);
    }
}

// ---------------------------------------------------------------------------
// bf16 MFMA GEMM (NT), m97 geometry: 128x128 tile, BK=64, 4 waves (2x2),
// single-buffer LDS (32 KB) + 2 __syncthreads per K-step. Latency hiding
// from MULTI-BLOCK residency (R10 post-mortem: this was the binding
// constraint, not the schedule). R11: __launch_bounds__(256,5) -> 5 blocks/CU
// (5 x 32 KB = the full 160 KB LDS pool; VGPR=64 permits 8 waves/SIMD).
// Zapprox = Xb @ WTb^T + be, fused candidate collection (packed keys).
//
// LDS [128 rows][64 bf16] per matrix, 16B-granule XOR swizzle
// slot = kgrp ^ (row&7) (R4/R6/R10-verified, 0 bank conflicts), written
// linearly by global_load_lds from pre-swizzled global addresses.
//
// XCD swizzle: XCD x owns M-tile window [x*8, x*8+8), sweeps bx ->
// A/B panels L2-resident (R10: FETCH 158 MB, HBM 564 GB/s, not BW-bound).
// ---------------------------------------------------------------------------
__global__ __launch_bounds__(256, 5) void gemm_topcand(
    const __hip_bfloat16* __restrict__ Xb,   // [M][K]
    const __hip_bfloat16* __restrict__ WTb,  // [F][K]
    const float* __restrict__ be,            // [F]
    int* __restrict__ cnt, unsigned int* __restrict__ cpack,
    int M, int K, int F)
{
    __shared__ short Al[128 * 64];
    __shared__ short Bl[128 * 64];

    const int tid = threadIdx.x;
    const int w = tid >> 6, l = tid & 63;
    const int wr = w >> 1, wc = w & 1;       // 2 x 2 wave grid

    // XCD-aware bijective block swizzle (grpM = 8 M-tiles per XCD window)
    const int M128 = M >> 7;                 // 64
    int by, bx;
    if ((M128 & 7) == 0) {
        const int grpM = M128 >> 3;          // 8
        const int j = blockIdx.x >> 3;
        by = (blockIdx.x & 7) * grpM + (j % grpM);
        bx = j / grpM;
    } else {
        by = blockIdx.x % M128;
        bx = blockIdx.x / M128;
    }
    const int bm = by * 128, bn = bx * 128;

    f32x4 acc[4][4];
#pragma unroll
    for (int m = 0; m < 4; ++m)
#pragma unroll
        for (int n = 0; n < 4; ++n) acc[m][n] = (f32x4)0.f;

    // staging: lane l covers row (chunk*8 + l>>3), 16B-group ((l&7) ^ (l>>3))
    const int s_r  = l >> 3;
    const int s_kg = (l & 7) ^ s_r;

    for (int kt = 0; kt < K; kt += 64) {
#pragma unroll
        for (int i_ = 0; i_ < 4; ++i_) {
            const int c = w * 4 + i_;                // chunk 0..15 (wave-uniform)
            const int r = c * 8 + s_r;               // tile row 0..127
            load_lds16(Xb  + (size_t)(bm + r) * K + kt + s_kg * 8, &Al[c * 512]);
            load_lds16(WTb + (size_t)(bn + r) * K + kt + s_kg * 8, &Bl[c * 512]);
        }
        __syncthreads();   // drains vmcnt(0): staged tile visible to all waves

#pragma unroll
        for (int kk = 0; kk < 2; ++kk) {
            const int kd = kk * 4 + (l >> 4);        // 16B-group wanted
            short8 a[4], b[4];
#pragma unroll
            for (int m = 0; m < 4; ++m) {
                const int r = wr * 64 + m * 16 + (l & 15);
                a[m] = *(const short8*)((const char*)Al + r * 128 + ((kd ^ (r & 7)) * 16));
            }
#pragma unroll
            for (int n = 0; n < 4; ++n) {
                const int r = wc * 64 + n * 16 + (l & 15);
                b[n] = *(const short8*)((const char*)Bl + r * 128 + ((kd ^ (r & 7)) * 16));
            }
#pragma unroll
            for (int m = 0; m < 4; ++m)
#pragma unroll
                for (int n = 0; n < 4; ++n)
                    acc[m][n] = __builtin_amdgcn_mfma_f32_16x16x32_bf16(a[m], b[n], acc[m][n], 0, 0, 0);
        }
        __syncthreads();   // readers done: safe to overwrite next K-step
    }

    // epilogue: D row = bm + wr*64 + m*16 + (l>>4)*4 + r;
    // col = bn + wc*64 + n*16 + (l&15). Collect z > t as packed keys.
    const int rl = l >> 4, cl = l & 15;
#pragma unroll
    for (int n = 0; n < 4; ++n) {
        const int col = bn + wc * 64 + n * 16 + cl;
        const float bias = be[col];
#pragma unroll
        for (int m = 0; m < 4; ++m) {
            const int row0 = bm + wr * 64 + m * 16 + rl * 4;
#pragma unroll
            for (int r = 0; r < 4; ++r) {
                const float v = acc[m][n][r] + bias;
                if (v > TCOLLECT) {
                    unsigned q = (unsigned)((v - QBASE) * QSCALE);
                    if (q > 0x1FFFFu) q = 0x1FFFFu;
                    const unsigned key = (q << 15) | (unsigned)(0x7FFF - col);
                    const int row = row0 + r;
                    int p = atomicAdd(&cnt[row], 1);
                    if (p < CAND) cpack[(size_t)row * CAND + p] = key;
                }
            }
        }
    }
}

// ---------------------------------------------------------------------------
// Per row: sort packed candidates (desc = val desc, idx asc), find approx
// rank-64 value vb. approx > vb+DELTA -> provably in numpy's exact top-64;
// approx < vb-DELTA -> provably out. Band gets the f32 SEQUENTIAL fmaf
// rescore (bit-identical to the R2/R4-passing arithmetic -> matches np
// selection), ranked exactly. Fused decode with bf16 W_dec (R11: halves
// the 1.6 GB L3-resident gather; adds <=~2e-3 output error, 0.018 budget).
// ---------------------------------------------------------------------------
__global__ __launch_bounds__(256) void select_rescore_decode(
    const float* __restrict__ X,     // [M][K] f32
    const float* __restrict__ WTf,   // [F][K] f32
    const float* __restrict__ be,
    const __hip_bfloat16* __restrict__ Wdb,  // [F][Dout] bf16
    const float* __restrict__ bd,
    const int* __restrict__ cnt, const unsigned int* __restrict__ cpack,
    float* __restrict__ out, int K, int Dout)
{
    const int row = blockIdx.x;
    const int tid = threadIdx.x;

    __shared__ unsigned int cp[CAND];
    __shared__ float xs[768];
    __shared__ float bv[BANDCAP]; __shared__ int bi[BANDCAP];
    __shared__ float rw[TKK];     __shared__ int rf[TKK];
    __shared__ int s_nc, s_be;

    int c = cnt[row]; if (c > CAND) c = CAND;
    int npad = 128; while (npad < c) npad <<= 1;   // 128..512

    for (int i = tid; i < npad; i += 256)
        cp[i] = (i < c) ? cpack[(size_t)row * CAND + i] : 0u;  // 0 sorts last
    for (int i = tid; i < K; i += 256) xs[i] = X[(size_t)row * K + i];
    if (tid == 0) { s_nc = 0; s_be = npad; }
    __syncthreads();

    // bitonic sort desc on packed keys (canonicalizes atomic arrival order)
    for (int k = 2; k <= npad; k <<= 1)
        for (int j = k >> 1; j > 0; j >>= 1) {
            for (int i = tid; i < npad; i += 256) {
                const int p = i ^ j;
                if (p > i) {
                    unsigned a = cp[i], b2 = cp[p];
                    const bool sw = ((i & k) == 0) ? (b2 > a) : (b2 < a);
                    if (sw) { cp[i] = b2; cp[p] = a; }
                }
            }
            __syncthreads();
        }

    // band classification around approx rank-64 value
    const float vb  = key_val(cp[63]);
    const float vhi = vb + DELTA, vlo = vb - DELTA;
    for (int i = tid; i < npad; i += 256) {
        const float vi = key_val(cp[i]);
        const float vp = (i == 0) ? FLT_MAX : key_val(cp[i - 1]);
        if (vi <= vhi && vp > vhi) s_nc = i;   // unique transition (sorted desc)
        if (vi <  vlo && vp >= vlo) s_be = i;
    }
    __syncthreads();
    int nc = s_nc; if (nc > 63) nc = 63;
    int nb = s_be - nc; if (nb > BANDCAP) nb = BANDCAP; if (nb < 0) nb = 0;

    // exact rescore of band only: f32 sequential fmaf, k ascending (np-matching)
    for (int j = tid; j < BANDCAP; j += 256) {
        if (j < nb) {
            const int f = key_idx(cp[nc + j]);
            const float* wrow = WTf + (size_t)f * K;
            float s = 0.f;
            for (int e = 0; e < K; e += 4) {
                float4 wv = *(const float4*)(wrow + e);
                float4 xv = *(const float4*)(&xs[e]);
                s = fmaf(xv.x, wv.x, s);
                s = fmaf(xv.y, wv.y, s);
                s = fmaf(xv.z, wv.z, s);
                s = fmaf(xv.w, wv.w, s);
            }
            bv[j] = s + be[f];
            bi[j] = f;
        } else { bv[j] = -FLT_MAX; bi[j] = INT_MAX; }
    }
    __syncthreads();

    // sort band by (exact desc, idx asc)
    for (int k = 2; k <= BANDCAP; k <<= 1)
        for (int j2 = k >> 1; j2 > 0; j2 >>= 1) {
            for (int i = tid; i < BANDCAP; i += 256) {
                const int p = i ^ j2;
                if (p > i) {
                    float v1 = bv[i], v2 = bv[p]; int i1 = bi[i], i2 = bi[p];
                    const bool gt = (v2 > v1) || (v2 == v1 && i2 < i1);
                    const bool sw = ((i & k) == 0) ? gt : !gt;
                    if (sw) { bv[i] = v2; bv[p] = v1; bi[i] = i2; bi[p] = i1; }
                }
            }
            __syncthreads();
        }

    // final top-64 = certain (approx values) + top-(64-nc) of band (exact values)
    if (tid < TKK) {
        float v; int f;
        if (tid < nc) { const unsigned key = cp[tid]; f = key_idx(key); v = key_val(key); }
        else          { const int r = tid - nc;       f = bi[r];        v = bv[r]; }
        if (f == INT_MAX) { f = 0; v = 0.f; }   // degenerate guard (never fires)
        rw[tid] = fmaxf(v, 0.f);
        rf[tid] = f;
    }
    __syncthreads();

    // fused decode: out[row,:] = sum_j rw[j] * Wdb[rf[j],:] + bd   (bf16 gather)
    for (int cc = tid * 4; cc < Dout; cc += 1024) {
        float4 a = *(const float4*)(bd + cc);
#pragma unroll 8
        for (int j = 0; j < TKK; ++j) {
            const float wgt = rw[j];
            ushort4 wv = *(const ushort4*)(Wdb + (size_t)rf[j] * Dout + cc);
            a.x = fmaf(wgt, bf2f(wv.x), a.x);
            a.y = fmaf(wgt, bf2f(wv.y), a.y);
            a.z = fmaf(wgt, bf2f(wv.z), a.z);
            a.w = fmaf(wgt, bf2f(wv.w), a.w);
        }
        *(float4*)(out + (size_t)row * Dout + cc) = a;
    }
}

// ---------------------------------------------------------------------------
extern "C" void kernel_launch(void* const* d_in, const int* in_sizes, int n_in,
                              void* d_out, int out_size, void* d_ws, size_t ws_size,
                              hipStream_t stream)
{
    const float* x  = (const float*)d_in[0];
    const float* We = (const float*)d_in[1];
    const float* be = (const float*)d_in[2];
    const float* Wd = (const float*)d_in[3];
    const float* bd = (const float*)d_in[4];
    float* out = (float*)d_out;

    const int F    = in_sizes[2];          // 24576
    const int K    = in_sizes[1] / F;      // 768
    const int M    = in_sizes[0] / K;      // 8192
    const int Dout = in_sizes[4];          // 768

    char* p = (char*)d_ws;
    __hip_bfloat16* Xb  = (__hip_bfloat16*)p; p += (size_t)M * K * 2;
    __hip_bfloat16* WTb = (__hip_bfloat16*)p; p += (size_t)F * K * 2;
    float*          WTf = (float*)p;          p += (size_t)F * K * 4;
    int*            cnt = (int*)p;            p += (size_t)M * 4;
    unsigned int*   cpk = (unsigned int*)p;   /* p += (size_t)M * CAND * 4; */

    // Wd-bf16 overlays the WTb region (identical byte size F*K*2 == F*Dout*2):
    // WTb is dead after gemm_topcand; stream order gemm -> cvt -> select.
    __hip_bfloat16* Wdb = WTb;

    hipMemsetAsync(cnt, 0, (size_t)M * 4, stream);

    cvt_bf16<<<(int)(((size_t)M * K / 4 + 255) / 256), 256, 0, stream>>>(
        x, Xb, (size_t)M * K);
    transpose_W<<<dim3(F / 32, K / 32), 256, 0, stream>>>(We, WTf, WTb, K, F);

    gemm_topcand<<<(M / 128) * (F / 128), 256, 0, stream>>>(
        Xb, WTb, be, cnt, cpk, M, K, F);

    cvt_bf16<<<(int)(((size_t)F * Dout / 4 + 255) / 256), 256, 0, stream>>>(
        Wd, Wdb, (size_t)F * Dout);

    select_rescore_decode<<<M, 256, 0, stream>>>(
        x, WTf, be, Wdb, bd, cnt, cpk, out, K, Dout);
}

// Round 12
// 664.572 us; speedup vs baseline: 1.9851x; 1.9851x over previous
//
#include <hip/hip_runtime.h>
#include <hip/hip_bf16.h>
#include <cfloat>
#include <climits>

typedef short short8 __attribute__((ext_vector_type(8)));
typedef float f32x4 __attribute__((ext_vector_type(4)));

#define TKK 64
#define CAND 512        // candidate cap per row (mean ~231 at t=2.35, 18 sigma headroom)
#define BANDCAP 128     // padded sort width for boundary band (band mean ~16)
#define TCOLLECT 2.35f  // collection threshold on approx (bf16-screen) z
#define QBASE 2.34f
#define QSCALE 16384.0f
#define DELTA 0.04f     // half-width of ambiguity band (~25 sigma of approx error)

// direct global->LDS async copy, 16B per lane, LDS dst = wave-uniform base + lane*16
__device__ __forceinline__ void load_lds16(const void* g, void* l) {
    __builtin_amdgcn_global_load_lds(
        (const __attribute__((address_space(1))) unsigned int*)g,
        (__attribute__((address_space(3))) unsigned int*)l, 16, 0, 0);
}

// packed candidate key: [31:15] quantized approx value, [14:0] = 0x7FFF - idx
__device__ __forceinline__ float key_val(unsigned k) {
    return (float)(k >> 15) * (1.0f / QSCALE) + QBASE;
}
__device__ __forceinline__ int key_idx(unsigned k) {
    return 0x7FFF - (int)(k & 0x7FFFu);
}

__device__ __forceinline__ float bf2f(unsigned short u) {
    return __uint_as_float((unsigned)u << 16);
}

// ---------------------------------------------------------------------------
// prep: f32 -> bf16 elementwise (used for x and for W_dec)
// ---------------------------------------------------------------------------
__global__ __launch_bounds__(256) void cvt_bf16(const float* __restrict__ X,
                                                __hip_bfloat16* __restrict__ Xb,
                                                size_t n)
{
    size_t i = ((size_t)blockIdx.x * 256 + threadIdx.x) * 4;
    if (i + 3 < n) {
        float4 v = *(const float4*)(X + i);
        __hip_bfloat16 t[4] = { __float2bfloat16(v.x), __float2bfloat16(v.y),
                                __float2bfloat16(v.z), __float2bfloat16(v.w) };
        *(uint2*)(Xb + i) = *(uint2*)t;
    }
}

// ---------------------------------------------------------------------------
// prep: W_enc [K][F] -> WTf [F][K] (f32) and WTb [F][K] (bf16)
// ---------------------------------------------------------------------------
__global__ __launch_bounds__(256) void transpose_W(
    const float* __restrict__ W, float* __restrict__ WTf,
    __hip_bfloat16* __restrict__ WTb, int K, int F)
{
    __shared__ float t[32][33];
    const int x0 = blockIdx.x * 32;   // feature block
    const int y0 = blockIdx.y * 32;   // k block
    const int tx = threadIdx.x & 31, ty = threadIdx.x >> 5;  // 32 x 8
#pragma unroll
    for (int i = 0; i < 4; ++i)
        t[ty + i * 8][tx] = W[(size_t)(y0 + ty + i * 8) * F + x0 + tx];
    __syncthreads();
#pragma unroll
    for (int i = 0; i < 4; ++i) {
        float v = t[tx][ty + i * 8];
        size_t o = (size_t)(x0 + ty + i * 8) * K + y0 + tx;
        WTf[o] = v;
        WTb[o] = __float2bfloat16(v);
    }
}

// ---------------------------------------------------------------------------
// bf16 MFMA GEMM (NT), m97 geometry: 128x128 tile, BK=64, 4 waves (2x2),
// single-buffer LDS (32 KB) + 2 __syncthreads per K-step. R10-PROVEN:
// __launch_bounds__(256,4) -> VGPR 64 (no spill; acc[4][4] alone needs 64),
// 4 independent blocks/CU = the latency hiding. R11's (256,5) forced VGPR
// down to 48 -> accumulator spilled to scratch -> 2.9 GB writes, 2.6x slower.
// DO NOT raise the occupancy bound past the live-register floor.
// Zapprox = Xb @ WTb^T + be, fused candidate collection (packed keys).
//
// LDS [128 rows][64 bf16] per matrix, 16B-granule XOR swizzle
// slot = kgrp ^ (row&7) (R4/R6/R10-verified, 0 bank conflicts), written
// linearly by global_load_lds from pre-swizzled global addresses.
//
// XCD swizzle: XCD x owns M-tile window [x*8, x*8+8), sweeps bx ->
// A/B panels L2-resident (R10: FETCH 158 MB, HBM 564 GB/s, not BW-bound).
// ---------------------------------------------------------------------------
__global__ __launch_bounds__(256, 4) void gemm_topcand(
    const __hip_bfloat16* __restrict__ Xb,   // [M][K]
    const __hip_bfloat16* __restrict__ WTb,  // [F][K]
    const float* __restrict__ be,            // [F]
    int* __restrict__ cnt, unsigned int* __restrict__ cpack,
    int M, int K, int F)
{
    __shared__ short Al[128 * 64];
    __shared__ short Bl[128 * 64];

    const int tid = threadIdx.x;
    const int w = tid >> 6, l = tid & 63;
    const int wr = w >> 1, wc = w & 1;       // 2 x 2 wave grid

    // XCD-aware bijective block swizzle (grpM = 8 M-tiles per XCD window)
    const int M128 = M >> 7;                 // 64
    int by, bx;
    if ((M128 & 7) == 0) {
        const int grpM = M128 >> 3;          // 8
        const int j = blockIdx.x >> 3;
        by = (blockIdx.x & 7) * grpM + (j % grpM);
        bx = j / grpM;
    } else {
        by = blockIdx.x % M128;
        bx = blockIdx.x / M128;
    }
    const int bm = by * 128, bn = bx * 128;

    f32x4 acc[4][4];
#pragma unroll
    for (int m = 0; m < 4; ++m)
#pragma unroll
        for (int n = 0; n < 4; ++n) acc[m][n] = (f32x4)0.f;

    // staging: lane l covers row (chunk*8 + l>>3), 16B-group ((l&7) ^ (l>>3))
    const int s_r  = l >> 3;
    const int s_kg = (l & 7) ^ s_r;

    for (int kt = 0; kt < K; kt += 64) {
#pragma unroll
        for (int i_ = 0; i_ < 4; ++i_) {
            const int c = w * 4 + i_;                // chunk 0..15 (wave-uniform)
            const int r = c * 8 + s_r;               // tile row 0..127
            load_lds16(Xb  + (size_t)(bm + r) * K + kt + s_kg * 8, &Al[c * 512]);
            load_lds16(WTb + (size_t)(bn + r) * K + kt + s_kg * 8, &Bl[c * 512]);
        }
        __syncthreads();   // drains vmcnt(0): staged tile visible to all waves

#pragma unroll
        for (int kk = 0; kk < 2; ++kk) {
            const int kd = kk * 4 + (l >> 4);        // 16B-group wanted
            short8 a[4], b[4];
#pragma unroll
            for (int m = 0; m < 4; ++m) {
                const int r = wr * 64 + m * 16 + (l & 15);
                a[m] = *(const short8*)((const char*)Al + r * 128 + ((kd ^ (r & 7)) * 16));
            }
#pragma unroll
            for (int n = 0; n < 4; ++n) {
                const int r = wc * 64 + n * 16 + (l & 15);
                b[n] = *(const short8*)((const char*)Bl + r * 128 + ((kd ^ (r & 7)) * 16));
            }
#pragma unroll
            for (int m = 0; m < 4; ++m)
#pragma unroll
                for (int n = 0; n < 4; ++n)
                    acc[m][n] = __builtin_amdgcn_mfma_f32_16x16x32_bf16(a[m], b[n], acc[m][n], 0, 0, 0);
        }
        __syncthreads();   // readers done: safe to overwrite next K-step
    }

    // epilogue: D row = bm + wr*64 + m*16 + (l>>4)*4 + r;
    // col = bn + wc*64 + n*16 + (l&15). Collect z > t as packed keys.
    const int rl = l >> 4, cl = l & 15;
#pragma unroll
    for (int n = 0; n < 4; ++n) {
        const int col = bn + wc * 64 + n * 16 + cl;
        const float bias = be[col];
#pragma unroll
        for (int m = 0; m < 4; ++m) {
            const int row0 = bm + wr * 64 + m * 16 + rl * 4;
#pragma unroll
            for (int r = 0; r < 4; ++r) {
                const float v = acc[m][n][r] + bias;
                if (v > TCOLLECT) {
                    unsigned q = (unsigned)((v - QBASE) * QSCALE);
                    if (q > 0x1FFFFu) q = 0x1FFFFu;
                    const unsigned key = (q << 15) | (unsigned)(0x7FFF - col);
                    const int row = row0 + r;
                    int p = atomicAdd(&cnt[row], 1);
                    if (p < CAND) cpack[(size_t)row * CAND + p] = key;
                }
            }
        }
    }
}

// ---------------------------------------------------------------------------
// Per row: sort packed candidates (desc = val desc, idx asc), find approx
// rank-64 value vb. approx > vb+DELTA -> provably in numpy's exact top-64;
// approx < vb-DELTA -> provably out. Band gets the f32 SEQUENTIAL fmaf
// rescore (bit-identical to the R2/R4-passing arithmetic -> matches np
// selection), ranked exactly. Fused decode with bf16 W_dec (R11-proven:
// halves the 1.6 GB L3-resident gather, ~110us saved; error ~2e-3 of the
// 0.018 budget).
// ---------------------------------------------------------------------------
__global__ __launch_bounds__(256) void select_rescore_decode(
    const float* __restrict__ X,     // [M][K] f32
    const float* __restrict__ WTf,   // [F][K] f32
    const float* __restrict__ be,
    const __hip_bfloat16* __restrict__ Wdb,  // [F][Dout] bf16
    const float* __restrict__ bd,
    const int* __restrict__ cnt, const unsigned int* __restrict__ cpack,
    float* __restrict__ out, int K, int Dout)
{
    const int row = blockIdx.x;
    const int tid = threadIdx.x;

    __shared__ unsigned int cp[CAND];
    __shared__ float xs[768];
    __shared__ float bv[BANDCAP]; __shared__ int bi[BANDCAP];
    __shared__ float rw[TKK];     __shared__ int rf[TKK];
    __shared__ int s_nc, s_be;

    int c = cnt[row]; if (c > CAND) c = CAND;
    int npad = 128; while (npad < c) npad <<= 1;   // 128..512

    for (int i = tid; i < npad; i += 256)
        cp[i] = (i < c) ? cpack[(size_t)row * CAND + i] : 0u;  // 0 sorts last
    for (int i = tid; i < K; i += 256) xs[i] = X[(size_t)row * K + i];
    if (tid == 0) { s_nc = 0; s_be = npad; }
    __syncthreads();

    // bitonic sort desc on packed keys (canonicalizes atomic arrival order)
    for (int k = 2; k <= npad; k <<= 1)
        for (int j = k >> 1; j > 0; j >>= 1) {
            for (int i = tid; i < npad; i += 256) {
                const int p = i ^ j;
                if (p > i) {
                    unsigned a = cp[i], b2 = cp[p];
                    const bool sw = ((i & k) == 0) ? (b2 > a) : (b2 < a);
                    if (sw) { cp[i] = b2; cp[p] = a; }
                }
            }
            __syncthreads();
        }

    // band classification around approx rank-64 value
    const float vb  = key_val(cp[63]);
    const float vhi = vb + DELTA, vlo = vb - DELTA;
    for (int i = tid; i < npad; i += 256) {
        const float vi = key_val(cp[i]);
        const float vp = (i == 0) ? FLT_MAX : key_val(cp[i - 1]);
        if (vi <= vhi && vp > vhi) s_nc = i;   // unique transition (sorted desc)
        if (vi <  vlo && vp >= vlo) s_be = i;
    }
    __syncthreads();
    int nc = s_nc; if (nc > 63) nc = 63;
    int nb = s_be - nc; if (nb > BANDCAP) nb = BANDCAP; if (nb < 0) nb = 0;

    // exact rescore of band only: f32 sequential fmaf, k ascending (np-matching)
    for (int j = tid; j < BANDCAP; j += 256) {
        if (j < nb) {
            const int f = key_idx(cp[nc + j]);
            const float* wrow = WTf + (size_t)f * K;
            float s = 0.f;
            for (int e = 0; e < K; e += 4) {
                float4 wv = *(const float4*)(wrow + e);
                float4 xv = *(const float4*)(&xs[e]);
                s = fmaf(xv.x, wv.x, s);
                s = fmaf(xv.y, wv.y, s);
                s = fmaf(xv.z, wv.z, s);
                s = fmaf(xv.w, wv.w, s);
            }
            bv[j] = s + be[f];
            bi[j] = f;
        } else { bv[j] = -FLT_MAX; bi[j] = INT_MAX; }
    }
    __syncthreads();

    // sort band by (exact desc, idx asc)
    for (int k = 2; k <= BANDCAP; k <<= 1)
        for (int j2 = k >> 1; j2 > 0; j2 >>= 1) {
            for (int i = tid; i < BANDCAP; i += 256) {
                const int p = i ^ j2;
                if (p > i) {
                    float v1 = bv[i], v2 = bv[p]; int i1 = bi[i], i2 = bi[p];
                    const bool gt = (v2 > v1) || (v2 == v1 && i2 < i1);
                    const bool sw = ((i & k) == 0) ? gt : !gt;
                    if (sw) { bv[i] = v2; bv[p] = v1; bi[i] = i2; bi[p] = i1; }
                }
            }
            __syncthreads();
        }

    // final top-64 = certain (approx values) + top-(64-nc) of band (exact values)
    if (tid < TKK) {
        float v; int f;
        if (tid < nc) { const unsigned key = cp[tid]; f = key_idx(key); v = key_val(key); }
        else          { const int r = tid - nc;       f = bi[r];        v = bv[r]; }
        if (f == INT_MAX) { f = 0; v = 0.f; }   // degenerate guard (never fires)
        rw[tid] = fmaxf(v, 0.f);
        rf[tid] = f;
    }
    __syncthreads();

    // fused decode: out[row,:] = sum_j rw[j] * Wdb[rf[j],:] + bd   (bf16 gather)
    for (int cc = tid * 4; cc < Dout; cc += 1024) {
        float4 a = *(const float4*)(bd + cc);
#pragma unroll 8
        for (int j = 0; j < TKK; ++j) {
            const float wgt = rw[j];
            ushort4 wv = *(const ushort4*)(Wdb + (size_t)rf[j] * Dout + cc);
            a.x = fmaf(wgt, bf2f(wv.x), a.x);
            a.y = fmaf(wgt, bf2f(wv.y), a.y);
            a.z = fmaf(wgt, bf2f(wv.z), a.z);
            a.w = fmaf(wgt, bf2f(wv.w), a.w);
        }
        *(float4*)(out + (size_t)row * Dout + cc) = a;
    }
}

// ---------------------------------------------------------------------------
extern "C" void kernel_launch(void* const* d_in, const int* in_sizes, int n_in,
                              void* d_out, int out_size, void* d_ws, size_t ws_size,
                              hipStream_t stream)
{
    const float* x  = (const float*)d_in[0];
    const float* We = (const float*)d_in[1];
    const float* be = (const float*)d_in[2];
    const float* Wd = (const float*)d_in[3];
    const float* bd = (const float*)d_in[4];
    float* out = (float*)d_out;

    const int F    = in_sizes[2];          // 24576
    const int K    = in_sizes[1] / F;      // 768
    const int M    = in_sizes[0] / K;      // 8192
    const int Dout = in_sizes[4];          // 768

    char* p = (char*)d_ws;
    __hip_bfloat16* Xb  = (__hip_bfloat16*)p; p += (size_t)M * K * 2;
    __hip_bfloat16* WTb = (__hip_bfloat16*)p; p += (size_t)F * K * 2;
    float*          WTf = (float*)p;          p += (size_t)F * K * 4;
    int*            cnt = (int*)p;            p += (size_t)M * 4;
    unsigned int*   cpk = (unsigned int*)p;   /* p += (size_t)M * CAND * 4; */

    // Wd-bf16 overlays the WTb region (identical byte size F*K*2 == F*Dout*2):
    // WTb is dead after gemm_topcand; stream order gemm -> cvt -> select.
    __hip_bfloat16* Wdb = WTb;

    hipMemsetAsync(cnt, 0, (size_t)M * 4, stream);

    cvt_bf16<<<(int)(((size_t)M * K / 4 + 255) / 256), 256, 0, stream>>>(
        x, Xb, (size_t)M * K);
    transpose_W<<<dim3(F / 32, K / 32), 256, 0, stream>>>(We, WTf, WTb, K, F);

    gemm_topcand<<<(M / 128) * (F / 128), 256, 0, stream>>>(
        Xb, WTb, be, cnt, cpk, M, K, F);

    cvt_bf16<<<(int)(((size_t)F * Dout / 4 + 255) / 256), 256, 0, stream>>>(
        Wd, Wdb, (size_t)F * Dout);

    select_rescore_decode<<<M, 256, 0, stream>>>(
        x, WTf, be, Wdb, bd, cnt, cpk, out, K, Dout);
}